// Round 5
// baseline (132.001 us; speedup 1.0000x reference)
//
#include <hip/hip_runtime.h>

#define CCH   256
#define FH    96
#define FW    96
#define HW    (FH*FW)
#define SCALE 0.0625f

#define HROWS 21              // max window rows (span<=19 -> 21); hwin clamped
#define SQMAX 7               // max row stride in quads (runtime stride sQ <= 7)
#define PLANE (HROWS*SQMAX*4) // 588 floats per wave plane (fixed alloc, runtime stride)
#define WCH   32              // channels per wave (block = 128ch half-roi, 4 waves)

// R5 = R4 (adaptive width; 60us/dispatch) + BATCH-SORTED roi->XCD placement.
// Whole grid is exactly co-resident (2048x256 = 256CU x 2048thr), so blockIdx
// only controls XCD placement. R4's per-XCD roi set was random over 4 batch
// planes (coverage 1.1x -> every window byte a compulsory L2 miss ->
// FETCH=100MB ~= 2.6x the 38MB feature map). Bucket kernel sorts rois by
// batch into d_ws; XCD-pair p=xcd>>1 takes sorted chunk [p*256,p*256+256)
// (~= one batch, 4.5x window overlap on ONE 9.2Kpx plane), half-channels per
// XCD. Per-XCD unique bytes ~= one 128ch slab ~=5MB -> FETCH ~45-60MB.
// Perm order within batch is atomic-nondeterministic; correctness independent
// (each roi processed once, disjoint out region). Fallback: ws too small ->
// identity chunks (contiguous k), same structure.
// Register deep-prefetch remains DEAD (R1 sunk / R3 spilled). DS-pipe ~70%
// busy (100Kcy/CU) - next lever if this hits its predicted FETCH.
__global__ void bucket_rois(const float* __restrict__ rois, int* __restrict__ perm, int K)
{
    __shared__ int cnt[4], base[4];
    const int t = threadIdx.x;
    if (t < 4) cnt[t] = 0;
    __syncthreads();
    int b = 0, pos = 0;
    if (t < K) {
        b   = min(max((int)rois[t*5], 0), 3);
        pos = atomicAdd(&cnt[b], 1);
    }
    __syncthreads();
    if (t == 0) {
        int s = 0;
        #pragma unroll
        for (int i = 0; i < 4; ++i) { base[i] = s; s += cnt[i]; }
    }
    __syncthreads();
    if (t < K) perm[base[b] + pos] = t;
}

__global__ __launch_bounds__(256, 8)
void roialign_kernel(const float* __restrict__ feat,
                     const float* __restrict__ rois,
                     float* __restrict__ out,
                     const int* __restrict__ perm)
{
    __shared__ __align__(16) float win[4 * PLANE];
    __shared__ int   s_lo[2][14];
    __shared__ float s_wl[2][14], s_wh[2][14];

    // XCD-pair chunking: xcd = blockIdx&7 (CP round-robin), pair p = xcd>>1
    // owns sorted-roi chunk [p*256, p*256+256) ~= one batch; half = xcd&1.
    const int xcd  = blockIdx.x & 7;
    const int j    = blockIdx.x >> 3;              // 0..255
    const int q    = ((xcd >> 1) << 8) + j;        // sorted-roi index
    const int half = xcd & 1;
    const int k    = perm ? perm[q] : q;

    const int tid  = threadIdx.x;
    const int w    = tid >> 6;
    const int ll   = tid & 63;

    // ---------- Phase A: per-roi sample coords ----------
    const float x1 = rois[k*5+1] * SCALE;
    const float y1 = rois[k*5+2] * SCALE;
    const float x2 = rois[k*5+3] * SCALE;
    const float y2 = rois[k*5+4] * SCALE;
    const int   b  = (int)rois[k*5+0];
    const float binw = fmaxf(x2 - x1, 1.0f) * (1.0f/7.0f);
    const float binh = fmaxf(y2 - y1, 1.0f) * (1.0f/7.0f);

    if (tid < 28) {
        const int   axis  = (tid >= 14) ? 1 : 0;
        const int   g     = axis ? tid - 14 : tid;
        const float start = axis ? x1 : y1;
        const float bsz   = axis ? binw : binh;
        const float offs  = (float)(g >> 1) + 0.25f + 0.5f*(float)(g & 1);
        const float coord = start + bsz * offs;
        const bool  valid = (coord >= -1.0f) && (coord <= 96.0f);
        const float cc    = fminf(fmaxf(coord, 0.0f), 95.0f);
        const float lof   = floorf(cc);
        const float frac  = cc - lof;
        const float v     = valid ? 1.0f : 0.0f;
        s_lo[axis][g] = (int)lof;
        s_wl[axis][g] = (1.0f - frac) * v;
        s_wh[axis][g] = frac * v;
    }
    __syncthreads();   // the ONLY barrier

    // ---------- adaptive window geometry (block-uniform) ----------
    const int row0   = s_lo[0][0];
    const int col0   = s_lo[1][0] & ~3;               // 16B-aligned left edge
    const int colEnd = min(s_lo[1][13] + 1, FW-1);    // rightmost tap column
    const int width  = colEnd - col0 + 1;             // 1..24
    const int cwq    = min((width + 3) >> 2, 6);      // data quads per row, 1..6
    const int sQ     = ((cwq + 1) & ~1) | 1;          // row stride quads: 3,3,5,5,7,7
    const int RS     = sQ * 4;                        // row stride in floats
    int hw_          = min(s_lo[0][13] + 1, FH-1) - row0 + 1;
    const int hwin   = min(hw_, HROWS);               // defensive clamp
    const int nslot  = hwin * cwq;                    // float4 slots, <=126

    float* const wp = &win[w * PLANE];

    // Zero this wave's full plane once. Pad quads (q >= cwq) are never
    // re-written -> stay 0 for weight-0 taps.
    {
        const float4 z = make_float4(0.f, 0.f, 0.f, 0.f);
        #pragma unroll
        for (int jj = 0; jj < 3; ++jj) {
            const int qq = ll + 64*jj;
            if (qq < PLANE/4) *(float4*)&wp[qq*4] = z;
        }
    }

    // ---------- Phase B: tap addresses & pre-scaled weights (channel-invariant) ----------
    const bool active = ll < 49;
    const int  p  = active ? ll : 0;
    const int  oy = p / 7;
    const int  ox = p - oy*7;

    int   aL[4], aH[4];
    float w00[4], w01[4], w10[4], w11[4];
    #pragma unroll
    for (int sy = 0; sy < 2; ++sy) {
        const int   gy  = 2*oy + sy;
        const int   rlo = min(s_lo[0][gy] - row0,                 HROWS-1);
        const int   rhi = min(min(s_lo[0][gy]+1, FH-1) - row0,    HROWS-1);
        const float wyl = s_wl[0][gy], wyh = s_wh[0][gy];
        #pragma unroll
        for (int sx = 0; sx < 2; ++sx) {
            const int   gx  = 2*ox + sx;
            const int   clo = min(s_lo[1][gx] - col0, RS-2);   // <=4*cwq-1 provable
            const float wxl = s_wl[1][gx], wxh = s_wh[1][gx];
            const int   s   = sy*2 + sx;
            aL[s] = rlo*RS + clo;
            aH[s] = rhi*RS + clo;
            w00[s] = wyl*wxl*0.25f;  w01[s] = wyl*wxh*0.25f;   // 0.25 = sample mean
            w10[s] = wyh*wxl*0.25f;  w11[s] = wyh*wxh*0.25f;
        }
    }

    // ---------- load-slot constants: slots ll and ll+64 of nslot ----------
    const int  sl1 = ll + 64;
    const int  r0  = ll  / cwq, q0 = ll  - r0*cwq;   // runtime div, once per lane
    const int  r1  = sl1 / cwq, q1 = sl1 - r1*cwq;
    const bool L0  = ll  < nslot;
    const bool L1  = sl1 < nslot;
    // Clamped: legal addresses even for predicated-off lanes.
    const int  goff0 = min(row0 + r0, FH-1)*FW + col0 + q0*4;  // col0+4*cwq<=96
    const int  goff1 = min(row0 + r1, FH-1)*FW + col0 + q1*4;
    const int  ld0   = min(r0, HROWS-1)*RS + q0*4;
    const int  ld1   = min(r1, HROWS-1)*RS + q1*4;

    const int    cb   = half*128 + w*WCH;
    const float* gch  = feat + (size_t)(b*CCH + cb) * HW;
    float*       outp = out  + ((size_t)k*CCH + cb)*49 + p;

    float4 st0, st1;
    if (L0) st0 = *(const float4*)(gch + goff0);
    if (L1) st1 = *(const float4*)(gch + goff1);

    for (int c = 0; c < WCH; ++c) {
        // vmcnt wait for this channel's loads lands on these writes; within-wave
        // ds ordering guarantees prior iteration's reads see old data first.
        if (L0) *(float4*)&wp[ld0] = st0;
        if (L1) *(float4*)&wp[ld1] = st1;

        if (c + 1 < WCH) {                       // next channel in flight during compute
            const float* gn = gch + (size_t)(c+1)*HW;
            if (L0) st0 = *(const float4*)(gn + goff0);
            if (L1) st1 = *(const float4*)(gn + goff1);
        }

        if (active) {
            // 4 independent chains; wp[a], wp[a+1] adjacent -> ds_read2_b32
            float t0 = w00[0]*wp[aL[0]]   + w01[0]*wp[aL[0]+1]
                     + w10[0]*wp[aH[0]]   + w11[0]*wp[aH[0]+1];
            float t1 = w00[1]*wp[aL[1]]   + w01[1]*wp[aL[1]+1]
                     + w10[1]*wp[aH[1]]   + w11[1]*wp[aH[1]+1];
            float t2 = w00[2]*wp[aL[2]]   + w01[2]*wp[aL[2]+1]
                     + w10[2]*wp[aH[2]]   + w11[2]*wp[aH[2]+1];
            float t3 = w00[3]*wp[aL[3]]   + w01[3]*wp[aL[3]+1]
                     + w10[3]*wp[aH[3]]   + w11[3]*wp[aH[3]+1];
            outp[0] = (t0 + t1) + (t2 + t3);
        }
        outp += 49;
    }
}

extern "C" void kernel_launch(void* const* d_in, const int* in_sizes, int n_in,
                              void* d_out, int out_size, void* d_ws, size_t ws_size,
                              hipStream_t stream) {
    const float* feat = (const float*)d_in[0];
    const float* rois = (const float*)d_in[1];
    float*       outp = (float*)d_out;
    const int K = in_sizes[1] / 5;   // 1024

    int* perm = nullptr;
    if (d_ws && ws_size >= (size_t)K * sizeof(int) && K <= 1024) {
        perm = (int*)d_ws;
        bucket_rois<<<1, 1024, 0, stream>>>(rois, perm, K);
    }
    roialign_kernel<<<K*2, 256, 0, stream>>>(feat, rois, outp, perm);
}